// Round 6
// baseline (364.904 us; speedup 1.0000x reference)
//
#include <hip/hip_runtime.h>
#include <hip/hip_bf16.h>

// Problem: B=2, L=2048, D=1024, H=16, HD=64. causal self-attention block.
// out = proj(attn(qkv(x)))
//
// Workspace layout (needs 48 MB):
//   [0,8M)   x_bf16      (4096,1024)
//   [8,14M)  WqkvT bf16  (3072,1024)   W^T so GEMM B-operand is [n][k]
//   [14,16M) WprojT bf16 (1024,1024)
//   [16,24M) q bf16 (B,H,L,HD)  pre-scaled by LOG2E/8 (softmax in base-2)
//   [24,32M) k bf16 (B,H,L,HD)
//   [32,40M) vT bf16 (B,H,HD,L)
//   [40,48M) O bf16 (B,L,H*HD) = (4096,1024)

typedef __attribute__((ext_vector_type(8))) short s16x8;
typedef __attribute__((ext_vector_type(4))) float f32x4;

__device__ __forceinline__ unsigned short f2b(float f) {
  __hip_bfloat16 h = __float2bfloat16(f);
  return *reinterpret_cast<unsigned short*>(&h);
}

// async global->LDS, 16B per lane. LDS dest is wave-uniform base (HW writes
// base + lane*16); global src is per-lane. Pointer cast = addrspacecast.
__device__ __forceinline__ void gl_lds16(const void* g, void* l) {
  __builtin_amdgcn_global_load_lds(
      (const __attribute__((address_space(1))) unsigned int*)g,
      (__attribute__((address_space(3))) unsigned int*)l,
      16, 0, 0);
}

// ---------------- converts ----------------

__global__ __launch_bounds__(256) void convert_f32_bf16(
    const float* __restrict__ in, unsigned short* __restrict__ out, int n4) {
  int i = blockIdx.x * 256 + threadIdx.x;
  if (i >= n4) return;
  float4 v = reinterpret_cast<const float4*>(in)[i];
  ushort4 o;
  o.x = f2b(v.x); o.y = f2b(v.y); o.z = f2b(v.z); o.w = f2b(v.w);
  reinterpret_cast<ushort4*>(out)[i] = o;
}

// out[c][r] = (bf16) in[r][c];  in is (R,C) fp32, out is (C,R) bf16
__global__ __launch_bounds__(256) void transpose_f32_bf16(
    const float* __restrict__ in, unsigned short* __restrict__ out, int R, int C) {
  __shared__ float tile[32][33];
  int cb = blockIdx.x * 32, rb = blockIdx.y * 32;
  int tx = threadIdx.x, ty = threadIdx.y;
  #pragma unroll
  for (int i = ty; i < 32; i += 8)
    tile[i][tx] = in[(size_t)(rb + i) * C + cb + tx];
  __syncthreads();
  #pragma unroll
  for (int i = ty; i < 32; i += 8)
    out[(size_t)(cb + i) * R + rb + tx] = f2b(tile[tx][i]);
}

// ---------------- GEMM 128x128 tile, K=1024, BK=64 ----------------
// A (M,1024) bf16 row-major; Bt (N,1024) bf16 row-major (= B^T).
// MODE 0: QKV epilogue (scatter q/k/vT, q scaled). MODE 1: fp32 out + bias.
template <int MODE>
__global__ __launch_bounds__(256) void gemm128(
    const unsigned short* __restrict__ A, const unsigned short* __restrict__ Bt,
    const float* __restrict__ bias, unsigned short* __restrict__ qOut,
    unsigned short* __restrict__ kOut, unsigned short* __restrict__ vOut,
    float* __restrict__ fOut) {
  __shared__ char sA[16384];
  __shared__ char sB[16384];
  const int tid = threadIdx.x;
  const int wid = tid >> 6, lane = tid & 63;
  const int lg = lane >> 4, lr = lane & 15;
  const int wr = wid >> 1, wc = wid & 1;
  const int mb = blockIdx.y, nb = blockIdx.x;

  f32x4 acc[4][4];
  #pragma unroll
  for (int i = 0; i < 4; ++i)
    #pragma unroll
    for (int j = 0; j < 4; ++j) acc[i][j] = f32x4{0.f, 0.f, 0.f, 0.f};

  for (int ks = 0; ks < 16; ++ks) {
    __syncthreads();
    // stage A,Bt tiles (16KB each): LDS linear, global source pre-swizzled
    #pragma unroll
    for (int r = 0; r < 4; ++r) {
      const int chunk = r * 4 + wid;
      const int o = chunk * 1024 + lane * 16;
      const int row = o >> 7;              // tile row 0..127
      const int c16 = (o >> 4) & 7;        // 16B slot within 128B row
      const int swz = (c16 ^ (row & 7)) << 4;
      gl_lds16((const char*)A + ((size_t)(mb * 128 + row) * 1024 + ks * 64) * 2 + swz,
               sA + chunk * 1024);
      gl_lds16((const char*)Bt + ((size_t)(nb * 128 + row) * 1024 + ks * 64) * 2 + swz,
               sB + chunk * 1024);
    }
    __syncthreads();
    #pragma unroll
    for (int kb = 0; kb < 2; ++kb) {
      s16x8 af[4], bfr[4];
      #pragma unroll
      for (int mt = 0; mt < 4; ++mt) {
        const int rrow = wr * 64 + mt * 16 + lr;
        const int off = kb * 64 + lg * 16;
        af[mt] = *(const s16x8*)(sA + rrow * 128 + (off ^ ((rrow & 7) << 4)));
      }
      #pragma unroll
      for (int nt = 0; nt < 4; ++nt) {
        const int rrow = wc * 64 + nt * 16 + lr;
        const int off = kb * 64 + lg * 16;
        bfr[nt] = *(const s16x8*)(sB + rrow * 128 + (off ^ ((rrow & 7) << 4)));
      }
      #pragma unroll
      for (int mt = 0; mt < 4; ++mt)
        #pragma unroll
        for (int nt = 0; nt < 4; ++nt)
          acc[mt][nt] = __builtin_amdgcn_mfma_f32_16x16x32_bf16(
              af[mt], bfr[nt], acc[mt][nt], 0, 0, 0);
    }
  }

  // epilogue. C layout: col = lane&15, row = (lane>>4)*4 + r
  #pragma unroll
  for (int mt = 0; mt < 4; ++mt)
    #pragma unroll
    for (int nt = 0; nt < 4; ++nt)
      #pragma unroll
      for (int r = 0; r < 4; ++r) {
        const int m = mb * 128 + wr * 64 + mt * 16 + lg * 4 + r;
        const int n = nb * 128 + wc * 64 + nt * 16 + lr;
        float val = acc[mt][nt][r] + bias[n];
        if constexpr (MODE == 0) {
          const int b = m >> 11, ml = m & 2047;
          if (n < 1024) {           // q, scaled by HD^-0.5 * LOG2E (base-2 softmax)
            const int h = n >> 6, d = n & 63;
            qOut[((size_t)((b * 16 + h) * 2048 + ml)) * 64 + d] =
                f2b(val * 0.18033688f);
          } else if (n < 2048) {    // k
            const int nn = n - 1024, h = nn >> 6, d = nn & 63;
            kOut[((size_t)((b * 16 + h) * 2048 + ml)) * 64 + d] = f2b(val);
          } else {                  // v -> transposed (B,H,HD,L)
            const int nn = n - 2048, h = nn >> 6, d = nn & 63;
            vOut[((size_t)((b * 16 + h) * 64 + d)) * 2048 + ml] = f2b(val);
          }
        } else {
          fOut[(size_t)m * 1024 + n] = val;
        }
      }
}

// ---------------- flash attention, kv-split ----------------
// One 256-thr block (4 waves) per (bh, qseg): 32 q-rows, kv tiles split
// across waves (t = wid, wid+4, ...). Per-wave online softmax; exact LDS
// merge at the end. Balanced: max 8 tiles/wave (vs 32 before). K/V direct
// from global (L2-resident, heads clustered per XCD slot). Base-2 softmax.
__global__ __launch_bounds__(256, 4) void attn_fwd(
    const unsigned short* __restrict__ Q, const unsigned short* __restrict__ Kb,
    const unsigned short* __restrict__ Vt, unsigned short* __restrict__ O) {
  __shared__ char sP[16384];        // per-wave [32 q][64 kv] bf16, swizzled
  __shared__ float obuf[32 * 68];   // merge accumulator, padded stride 68
  __shared__ float mlbuf[4][32][2]; // per-wave (m, l) per row
  __shared__ float lginv[32];       // 1 / l_global per row

  const int bid = blockIdx.x;
  const int idx = bid >> 3;
  const int bh = (bid & 7) * 4 + (idx & 3);  // cluster 4 heads per XCD slot
  const int qseg = 63 - (idx >> 2);          // heavy blocks first
  const int b = bh >> 4, h = bh & 15;
  const int tid = threadIdx.x;
  const int wid = tid >> 6, lane = tid & 63;
  const int lg = lane >> 4, lr = lane & 15;
  const int base = qseg * 32;

  // zero merge buffer (visible to all after the first merge barrier)
  for (int i = tid; i < 32 * 68; i += 256) obuf[i] = 0.f;

  // Q fragments (same 32 rows for all 4 waves)
  s16x8 qf[2][2];
  #pragma unroll
  for (int mt = 0; mt < 2; ++mt)
    #pragma unroll
    for (int kb = 0; kb < 2; ++kb) {
      const int row = base + mt * 16 + lr;
      qf[mt][kb] = *(const s16x8*)(Q + (size_t)(bh * 2048 + row) * 64 + kb * 32 + lg * 8);
    }

  f32x4 acc[2][4];
  float rm[2][4], rl[2][4];
  #pragma unroll
  for (int i = 0; i < 2; ++i)
    #pragma unroll
    for (int jj = 0; jj < 4; ++jj) {
      acc[i][jj] = f32x4{0.f, 0.f, 0.f, 0.f};
      rm[i][jj] = -INFINITY;
      rl[i][jj] = 0.f;
    }

  char* wbase = sP + wid * 4096;
  const int nkv = (qseg >> 1) + 1;

  for (int t = wid; t < nkv; t += 4) {
    const int kv0 = t * 64;

    // S = Q K^T  (32 q x 64 kv)
    f32x4 sfr[2][4];
    #pragma unroll
    for (int i = 0; i < 2; ++i)
      #pragma unroll
      for (int jj = 0; jj < 4; ++jj) sfr[i][jj] = f32x4{0.f, 0.f, 0.f, 0.f};
    #pragma unroll
    for (int kb = 0; kb < 2; ++kb) {
      s16x8 kf[4];
      #pragma unroll
      for (int nt = 0; nt < 4; ++nt)
        kf[nt] = *(const s16x8*)(Kb +
            (size_t)(bh * 2048 + kv0 + nt * 16 + lr) * 64 + kb * 32 + lg * 8);
      #pragma unroll
      for (int mt = 0; mt < 2; ++mt)
        #pragma unroll
        for (int nt = 0; nt < 4; ++nt)
          sfr[mt][nt] = __builtin_amdgcn_mfma_f32_16x16x32_bf16(
              qf[mt][kb], kf[nt], sfr[mt][nt], 0, 0, 0);
    }

    // issue V loads now so they overlap the softmax VALU chain
    s16x8 vf[2][4];
    #pragma unroll
    for (int kb = 0; kb < 2; ++kb)
      #pragma unroll
      for (int nt = 0; nt < 4; ++nt)
        vf[kb][nt] = *(const s16x8*)(Vt +
            (size_t)(bh * 64 + nt * 16 + lr) * 2048 + kv0 + kb * 32 + lg * 8);

    // mask + online softmax (base-2: S already scaled by LOG2E)
    #pragma unroll
    for (int mt = 0; mt < 2; ++mt) {
      #pragma unroll
      for (int r = 0; r < 4; ++r) {
        const int grow = base + mt * 16 + lg * 4 + r;
        float tmax = -INFINITY;
        #pragma unroll
        for (int nt = 0; nt < 4; ++nt) {
          const int col = kv0 + nt * 16 + lr;
          float s = sfr[mt][nt][r];
          if (col > grow) s = -INFINITY;
          sfr[mt][nt][r] = s;
          tmax = fmaxf(tmax, s);
        }
        tmax = fmaxf(tmax, __shfl_xor(tmax, 1));
        tmax = fmaxf(tmax, __shfl_xor(tmax, 2));
        tmax = fmaxf(tmax, __shfl_xor(tmax, 4));
        tmax = fmaxf(tmax, __shfl_xor(tmax, 8));
        const float mold = rm[mt][r];
        const float mnew = fmaxf(mold, tmax);
        const float alpha = exp2f(mold - mnew);
        float psum = 0.f;
        #pragma unroll
        for (int nt = 0; nt < 4; ++nt) {
          const float p = exp2f(sfr[mt][nt][r] - mnew);
          sfr[mt][nt][r] = p;
          psum += p;
        }
        psum += __shfl_xor(psum, 1);
        psum += __shfl_xor(psum, 2);
        psum += __shfl_xor(psum, 4);
        psum += __shfl_xor(psum, 8);
        rl[mt][r] = rl[mt][r] * alpha + psum;
        rm[mt][r] = mnew;
        #pragma unroll
        for (int nt = 0; nt < 4; ++nt) acc[mt][nt][r] *= alpha;
        // write P row (C-layout -> LDS), swizzled
        const int prow = mt * 16 + lg * 4 + r;
        #pragma unroll
        for (int nt = 0; nt < 4; ++nt) {
          const int pcolb = nt * 32 + lr * 2;
          *(unsigned short*)(wbase + prow * 128 + (pcolb ^ ((prow & 7) << 4))) =
              f2b(sfr[mt][nt][r]);
        }
      }
    }

    // PV: O += P V. P read back as A-fragments; vT rows give B-fragments.
    s16x8 pf[2][2];
    #pragma unroll
    for (int mt = 0; mt < 2; ++mt)
      #pragma unroll
      for (int kb = 0; kb < 2; ++kb) {
        const int prow = mt * 16 + lr;
        const int off = kb * 64 + lg * 16;
        pf[mt][kb] = *(const s16x8*)(wbase + prow * 128 + (off ^ ((prow & 7) << 4)));
      }
    #pragma unroll
    for (int mt = 0; mt < 2; ++mt)
      #pragma unroll
      for (int nt = 0; nt < 4; ++nt)
        #pragma unroll
        for (int kb = 0; kb < 2; ++kb)
          acc[mt][nt] = __builtin_amdgcn_mfma_f32_16x16x32_bf16(
              pf[mt][kb], vf[kb][nt], acc[mt][nt], 0, 0, 0);
  }

  // ---- merge the 4 partial (m, l, acc) sets ----
  // publish per-row (m, l); uniform across the 16 lr lanes, so lr==0 writes
  if (lr == 0) {
    #pragma unroll
    for (int mt = 0; mt < 2; ++mt)
      #pragma unroll
      for (int r = 0; r < 4; ++r) {
        const int row = mt * 16 + lg * 4 + r;
        mlbuf[wid][row][0] = rm[mt][r];
        mlbuf[wid][row][1] = rl[mt][r];
      }
  }
  __syncthreads();

  float beta[2][4];
  #pragma unroll
  for (int mt = 0; mt < 2; ++mt)
    #pragma unroll
    for (int r = 0; r < 4; ++r) {
      const int row = mt * 16 + lg * 4 + r;
      const float m0 = mlbuf[0][row][0], m1 = mlbuf[1][row][0];
      const float m2 = mlbuf[2][row][0], m3 = mlbuf[3][row][0];
      const float mg = fmaxf(fmaxf(m0, m1), fmaxf(m2, m3));
      const float lsum = mlbuf[0][row][1] * exp2f(m0 - mg)
                       + mlbuf[1][row][1] * exp2f(m1 - mg)
                       + mlbuf[2][row][1] * exp2f(m2 - mg)
                       + mlbuf[3][row][1] * exp2f(m3 - mg);
      beta[mt][r] = exp2f(rm[mt][r] - mg);
      if (wid == 0 && lr == 0) lginv[row] = 1.f / lsum;
    }

  // sequential accumulate (deterministic, no atomics)
  #pragma unroll
  for (int w = 0; w < 4; ++w) {
    if (wid == w) {
      #pragma unroll
      for (int mt = 0; mt < 2; ++mt)
        #pragma unroll
        for (int nt = 0; nt < 4; ++nt)
          #pragma unroll
          for (int r = 0; r < 4; ++r) {
            const int row = mt * 16 + lg * 4 + r;
            const int col = nt * 16 + lr;
            obuf[row * 68 + col] += acc[mt][nt][r] * beta[mt][r];
          }
    }
    __syncthreads();
  }

  // readout: wave w -> rows [8w, 8w+8), each lane 8 consecutive cols
  {
    const int row = (wid << 3) + (lane >> 3);
    const int c0 = (lane & 7) * 8;
    const float li = lginv[row];
    const float4 v0 = *(const float4*)&obuf[row * 68 + c0];
    const float4 v1 = *(const float4*)&obuf[row * 68 + c0 + 4];
    s16x8 o;
    o[0] = (short)f2b(v0.x * li); o[1] = (short)f2b(v0.y * li);
    o[2] = (short)f2b(v0.z * li); o[3] = (short)f2b(v0.w * li);
    o[4] = (short)f2b(v1.x * li); o[5] = (short)f2b(v1.y * li);
    o[6] = (short)f2b(v1.z * li); o[7] = (short)f2b(v1.w * li);
    const int grow = base + row;
    *(s16x8*)(O + (size_t)(b * 2048 + grow) * 1024 + h * 64 + c0) = o;
  }
}

// ---------------- launch ----------------

extern "C" void kernel_launch(void* const* d_in, const int* in_sizes, int n_in,
                              void* d_out, int out_size, void* d_ws, size_t ws_size,
                              hipStream_t stream) {
  const float* x     = (const float*)d_in[0];
  const float* Wqkv  = (const float*)d_in[1];
  const float* bqkv  = (const float*)d_in[2];
  const float* Wproj = (const float*)d_in[3];
  const float* bproj = (const float*)d_in[4];
  float* out = (float*)d_out;

  char* ws = (char*)d_ws;
  unsigned short* xb    = (unsigned short*)(ws);
  unsigned short* wqkvt = (unsigned short*)(ws + (8ull << 20));
  unsigned short* wprjt = (unsigned short*)(ws + (14ull << 20));
  unsigned short* qb    = (unsigned short*)(ws + (16ull << 20));
  unsigned short* kb    = (unsigned short*)(ws + (24ull << 20));
  unsigned short* vT    = (unsigned short*)(ws + (32ull << 20));
  unsigned short* Ob    = (unsigned short*)(ws + (40ull << 20));

  // x: 4096*1024 = 4,194,304 elems = 1,048,576 float4
  convert_f32_bf16<<<4096, 256, 0, stream>>>(x, xb, 1048576);
  transpose_f32_bf16<<<dim3(96, 32), dim3(32, 8), 0, stream>>>(Wqkv, wqkvt, 1024, 3072);
  transpose_f32_bf16<<<dim3(32, 32), dim3(32, 8), 0, stream>>>(Wproj, wprjt, 1024, 1024);
  gemm128<0><<<dim3(24, 32), 256, 0, stream>>>(xb, wqkvt, bqkv, qb, kb, vT, nullptr);
  attn_fwd<<<2048, 256, 0, stream>>>(qb, kb, vT, Ob);
  gemm128<1><<<dim3(8, 32), 256, 0, stream>>>(Ob, wprjt, bproj, nullptr, nullptr, nullptr, out);
}

// Round 10
// 257.262 us; speedup vs baseline: 1.4184x; 1.4184x over previous
//
#include <hip/hip_runtime.h>
#include <hip/hip_bf16.h>

// Problem: B=2, L=2048, D=1024, H=16, HD=64. causal self-attention block.
// out = proj(attn(qkv(x)))
//
// Workspace layout (needs 48 MB):
//   [0,8M)   x_bf16      (4096,1024)
//   [8,14M)  WqkvT bf16  (3072,1024)   W^T so GEMM B-operand is [n][k]
//   [14,16M) WprojT bf16 (1024,1024)
//   [16,24M) q bf16 (B,H,L,HD)  pre-scaled by LOG2E/8 (softmax in base-2)
//   [24,32M) k bf16 (B,H,L,HD)
//   [32,40M) vT bf16 (B,H,HD,L)
//   [40,48M) O bf16 (B,L,H*HD) = (4096,1024)

typedef __attribute__((ext_vector_type(8))) short s16x8;
typedef __attribute__((ext_vector_type(4))) float f32x4;

__device__ __forceinline__ unsigned short f2b(float f) {
  __hip_bfloat16 h = __float2bfloat16(f);
  return *reinterpret_cast<unsigned short*>(&h);
}

// async global->LDS, 16B per lane. LDS dest is wave-uniform base (HW writes
// base + lane*16); global src is per-lane. Pointer cast = addrspacecast.
__device__ __forceinline__ void gl_lds16(const void* g, void* l) {
  __builtin_amdgcn_global_load_lds(
      (const __attribute__((address_space(1))) unsigned int*)g,
      (__attribute__((address_space(3))) unsigned int*)l,
      16, 0, 0);
}

// ---------------- converts ----------------

__global__ __launch_bounds__(256) void convert_f32_bf16(
    const float* __restrict__ in, unsigned short* __restrict__ out, int n4) {
  int i = blockIdx.x * 256 + threadIdx.x;
  if (i >= n4) return;
  float4 v = reinterpret_cast<const float4*>(in)[i];
  ushort4 o;
  o.x = f2b(v.x); o.y = f2b(v.y); o.z = f2b(v.z); o.w = f2b(v.w);
  reinterpret_cast<ushort4*>(out)[i] = o;
}

// out[c][r] = (bf16) in[r][c];  in is (R,C) fp32, out is (C,R) bf16
__global__ __launch_bounds__(256) void transpose_f32_bf16(
    const float* __restrict__ in, unsigned short* __restrict__ out, int R, int C) {
  __shared__ float tile[32][33];
  int cb = blockIdx.x * 32, rb = blockIdx.y * 32;
  int tx = threadIdx.x, ty = threadIdx.y;
  #pragma unroll
  for (int i = ty; i < 32; i += 8)
    tile[i][tx] = in[(size_t)(rb + i) * C + cb + tx];
  __syncthreads();
  #pragma unroll
  for (int i = ty; i < 32; i += 8)
    out[(size_t)(cb + i) * R + rb + tx] = f2b(tile[tx][i]);
}

// ---------------- GEMM 128x128 tile, K=1024, BK=64 ----------------
// A (M,1024) bf16 row-major; Bt (N,1024) bf16 row-major (= B^T).
// MODE 0: QKV epilogue (scatter q/k/vT, q scaled). MODE 1: fp32 out + bias.
template <int MODE>
__global__ __launch_bounds__(256) void gemm128(
    const unsigned short* __restrict__ A, const unsigned short* __restrict__ Bt,
    const float* __restrict__ bias, unsigned short* __restrict__ qOut,
    unsigned short* __restrict__ kOut, unsigned short* __restrict__ vOut,
    float* __restrict__ fOut) {
  __shared__ char sA[16384];
  __shared__ char sB[16384];
  const int tid = threadIdx.x;
  const int wid = tid >> 6, lane = tid & 63;
  const int lg = lane >> 4, lr = lane & 15;
  const int wr = wid >> 1, wc = wid & 1;
  const int mb = blockIdx.y, nb = blockIdx.x;

  f32x4 acc[4][4];
  #pragma unroll
  for (int i = 0; i < 4; ++i)
    #pragma unroll
    for (int j = 0; j < 4; ++j) acc[i][j] = f32x4{0.f, 0.f, 0.f, 0.f};

  for (int ks = 0; ks < 16; ++ks) {
    __syncthreads();
    // stage A,Bt tiles (16KB each): LDS linear, global source pre-swizzled
    #pragma unroll
    for (int r = 0; r < 4; ++r) {
      const int chunk = r * 4 + wid;
      const int o = chunk * 1024 + lane * 16;
      const int row = o >> 7;              // tile row 0..127
      const int c16 = (o >> 4) & 7;        // 16B slot within 128B row
      const int swz = (c16 ^ (row & 7)) << 4;
      gl_lds16((const char*)A + ((size_t)(mb * 128 + row) * 1024 + ks * 64) * 2 + swz,
               sA + chunk * 1024);
      gl_lds16((const char*)Bt + ((size_t)(nb * 128 + row) * 1024 + ks * 64) * 2 + swz,
               sB + chunk * 1024);
    }
    __syncthreads();
    #pragma unroll
    for (int kb = 0; kb < 2; ++kb) {
      s16x8 af[4], bfr[4];
      #pragma unroll
      for (int mt = 0; mt < 4; ++mt) {
        const int rrow = wr * 64 + mt * 16 + lr;
        const int off = kb * 64 + lg * 16;
        af[mt] = *(const s16x8*)(sA + rrow * 128 + (off ^ ((rrow & 7) << 4)));
      }
      #pragma unroll
      for (int nt = 0; nt < 4; ++nt) {
        const int rrow = wc * 64 + nt * 16 + lr;
        const int off = kb * 64 + lg * 16;
        bfr[nt] = *(const s16x8*)(sB + rrow * 128 + (off ^ ((rrow & 7) << 4)));
      }
      #pragma unroll
      for (int mt = 0; mt < 4; ++mt)
        #pragma unroll
        for (int nt = 0; nt < 4; ++nt)
          acc[mt][nt] = __builtin_amdgcn_mfma_f32_16x16x32_bf16(
              af[mt], bfr[nt], acc[mt][nt], 0, 0, 0);
    }
  }

  // epilogue. C layout: col = lane&15, row = (lane>>4)*4 + r
  #pragma unroll
  for (int mt = 0; mt < 4; ++mt)
    #pragma unroll
    for (int nt = 0; nt < 4; ++nt)
      #pragma unroll
      for (int r = 0; r < 4; ++r) {
        const int m = mb * 128 + wr * 64 + mt * 16 + lg * 4 + r;
        const int n = nb * 128 + wc * 64 + nt * 16 + lr;
        float val = acc[mt][nt][r] + bias[n];
        if constexpr (MODE == 0) {
          const int b = m >> 11, ml = m & 2047;
          if (n < 1024) {           // q, scaled by HD^-0.5 * LOG2E (base-2 softmax)
            const int h = n >> 6, d = n & 63;
            qOut[((size_t)((b * 16 + h) * 2048 + ml)) * 64 + d] =
                f2b(val * 0.18033688f);
          } else if (n < 2048) {    // k
            const int nn = n - 1024, h = nn >> 6, d = nn & 63;
            kOut[((size_t)((b * 16 + h) * 2048 + ml)) * 64 + d] = f2b(val);
          } else {                  // v -> transposed (B,H,HD,L)
            const int nn = n - 2048, h = nn >> 6, d = nn & 63;
            vOut[((size_t)((b * 16 + h) * 64 + d)) * 2048 + ml] = f2b(val);
          }
        } else {
          fOut[(size_t)m * 1024 + n] = val;
        }
      }
}

// ---------------- flash attention, kv-split ----------------
// One 256-thr block (4 waves) per (bh, qseg): 32 q-rows, kv tiles split
// across waves (t = wid, wid+4, ...). Per-wave online softmax; exact LDS
// merge at the end. Balanced: max 8 tiles/wave. K/V direct from global
// (L2-resident, heads clustered per XCD slot). Base-2 softmax.
// launch_bounds(256,2): VGPR cap 256 — (256,4) forced VGPR=64 and spilled
// ~600 MB/dispatch to scratch (R6: FETCH 337MB, WRITE 276MB, 204us).
// Natural alloc ~140 VGPR -> 3 waves/SIMD, no spills.
__global__ __launch_bounds__(256, 2) void attn_fwd(
    const unsigned short* __restrict__ Q, const unsigned short* __restrict__ Kb,
    const unsigned short* __restrict__ Vt, unsigned short* __restrict__ O) {
  __shared__ char sP[16384];        // per-wave [32 q][64 kv] bf16, swizzled
  __shared__ float obuf[32 * 68];   // merge accumulator, padded stride 68
  __shared__ float mlbuf[4][32][2]; // per-wave (m, l) per row
  __shared__ float lginv[32];       // 1 / l_global per row

  const int bid = blockIdx.x;
  const int idx = bid >> 3;
  const int bh = (bid & 7) * 4 + (idx & 3);  // cluster 4 heads per XCD slot
  const int qseg = 63 - (idx >> 2);          // heavy blocks first
  const int b = bh >> 4, h = bh & 15;
  const int tid = threadIdx.x;
  const int wid = tid >> 6, lane = tid & 63;
  const int lg = lane >> 4, lr = lane & 15;
  const int base = qseg * 32;

  // zero merge buffer (visible to all after the first merge barrier)
  for (int i = tid; i < 32 * 68; i += 256) obuf[i] = 0.f;

  // Q fragments (same 32 rows for all 4 waves)
  s16x8 qf[2][2];
  #pragma unroll
  for (int mt = 0; mt < 2; ++mt)
    #pragma unroll
    for (int kb = 0; kb < 2; ++kb) {
      const int row = base + mt * 16 + lr;
      qf[mt][kb] = *(const s16x8*)(Q + (size_t)(bh * 2048 + row) * 64 + kb * 32 + lg * 8);
    }

  f32x4 acc[2][4];
  float rm[2][4], rl[2][4];
  #pragma unroll
  for (int i = 0; i < 2; ++i)
    #pragma unroll
    for (int jj = 0; jj < 4; ++jj) {
      acc[i][jj] = f32x4{0.f, 0.f, 0.f, 0.f};
      rm[i][jj] = -INFINITY;
      rl[i][jj] = 0.f;
    }

  char* wbase = sP + wid * 4096;
  const int nkv = (qseg >> 1) + 1;

  for (int t = wid; t < nkv; t += 4) {
    const int kv0 = t * 64;

    // S = Q K^T  (32 q x 64 kv)
    f32x4 sfr[2][4];
    #pragma unroll
    for (int i = 0; i < 2; ++i)
      #pragma unroll
      for (int jj = 0; jj < 4; ++jj) sfr[i][jj] = f32x4{0.f, 0.f, 0.f, 0.f};
    #pragma unroll
    for (int kb = 0; kb < 2; ++kb) {
      s16x8 kf[4];
      #pragma unroll
      for (int nt = 0; nt < 4; ++nt)
        kf[nt] = *(const s16x8*)(Kb +
            (size_t)(bh * 2048 + kv0 + nt * 16 + lr) * 64 + kb * 32 + lg * 8);
      #pragma unroll
      for (int mt = 0; mt < 2; ++mt)
        #pragma unroll
        for (int nt = 0; nt < 4; ++nt)
          sfr[mt][nt] = __builtin_amdgcn_mfma_f32_16x16x32_bf16(
              qf[mt][kb], kf[nt], sfr[mt][nt], 0, 0, 0);
    }

    // issue V loads now so they overlap the softmax VALU chain
    s16x8 vf[2][4];
    #pragma unroll
    for (int kb = 0; kb < 2; ++kb)
      #pragma unroll
      for (int nt = 0; nt < 4; ++nt)
        vf[kb][nt] = *(const s16x8*)(Vt +
            (size_t)(bh * 64 + nt * 16 + lr) * 2048 + kv0 + kb * 32 + lg * 8);

    // mask + online softmax (base-2: S already scaled by LOG2E)
    #pragma unroll
    for (int mt = 0; mt < 2; ++mt) {
      #pragma unroll
      for (int r = 0; r < 4; ++r) {
        const int grow = base + mt * 16 + lg * 4 + r;
        float tmax = -INFINITY;
        #pragma unroll
        for (int nt = 0; nt < 4; ++nt) {
          const int col = kv0 + nt * 16 + lr;
          float s = sfr[mt][nt][r];
          if (col > grow) s = -INFINITY;
          sfr[mt][nt][r] = s;
          tmax = fmaxf(tmax, s);
        }
        tmax = fmaxf(tmax, __shfl_xor(tmax, 1));
        tmax = fmaxf(tmax, __shfl_xor(tmax, 2));
        tmax = fmaxf(tmax, __shfl_xor(tmax, 4));
        tmax = fmaxf(tmax, __shfl_xor(tmax, 8));
        const float mold = rm[mt][r];
        const float mnew = fmaxf(mold, tmax);
        const float alpha = exp2f(mold - mnew);
        float psum = 0.f;
        #pragma unroll
        for (int nt = 0; nt < 4; ++nt) {
          const float p = exp2f(sfr[mt][nt][r] - mnew);
          sfr[mt][nt][r] = p;
          psum += p;
        }
        psum += __shfl_xor(psum, 1);
        psum += __shfl_xor(psum, 2);
        psum += __shfl_xor(psum, 4);
        psum += __shfl_xor(psum, 8);
        rl[mt][r] = rl[mt][r] * alpha + psum;
        rm[mt][r] = mnew;
        #pragma unroll
        for (int nt = 0; nt < 4; ++nt) acc[mt][nt][r] *= alpha;
        // write P row (C-layout -> LDS), swizzled
        const int prow = mt * 16 + lg * 4 + r;
        #pragma unroll
        for (int nt = 0; nt < 4; ++nt) {
          const int pcolb = nt * 32 + lr * 2;
          *(unsigned short*)(wbase + prow * 128 + (pcolb ^ ((prow & 7) << 4))) =
              f2b(sfr[mt][nt][r]);
        }
      }
    }

    // PV: O += P V. P read back as A-fragments; vT rows give B-fragments.
    s16x8 pf[2][2];
    #pragma unroll
    for (int mt = 0; mt < 2; ++mt)
      #pragma unroll
      for (int kb = 0; kb < 2; ++kb) {
        const int prow = mt * 16 + lr;
        const int off = kb * 64 + lg * 16;
        pf[mt][kb] = *(const s16x8*)(wbase + prow * 128 + (off ^ ((prow & 7) << 4)));
      }
    #pragma unroll
    for (int mt = 0; mt < 2; ++mt)
      #pragma unroll
      for (int nt = 0; nt < 4; ++nt)
        #pragma unroll
        for (int kb = 0; kb < 2; ++kb)
          acc[mt][nt] = __builtin_amdgcn_mfma_f32_16x16x32_bf16(
              pf[mt][kb], vf[kb][nt], acc[mt][nt], 0, 0, 0);
  }

  // ---- merge the 4 partial (m, l, acc) sets ----
  // publish per-row (m, l); uniform across the 16 lr lanes, so lr==0 writes
  if (lr == 0) {
    #pragma unroll
    for (int mt = 0; mt < 2; ++mt)
      #pragma unroll
      for (int r = 0; r < 4; ++r) {
        const int row = mt * 16 + lg * 4 + r;
        mlbuf[wid][row][0] = rm[mt][r];
        mlbuf[wid][row][1] = rl[mt][r];
      }
  }
  __syncthreads();

  float beta[2][4];
  #pragma unroll
  for (int mt = 0; mt < 2; ++mt)
    #pragma unroll
    for (int r = 0; r < 4; ++r) {
      const int row = mt * 16 + lg * 4 + r;
      const float m0 = mlbuf[0][row][0], m1 = mlbuf[1][row][0];
      const float m2 = mlbuf[2][row][0], m3 = mlbuf[3][row][0];
      const float mg = fmaxf(fmaxf(m0, m1), fmaxf(m2, m3));
      const float lsum = mlbuf[0][row][1] * exp2f(m0 - mg)
                       + mlbuf[1][row][1] * exp2f(m1 - mg)
                       + mlbuf[2][row][1] * exp2f(m2 - mg)
                       + mlbuf[3][row][1] * exp2f(m3 - mg);
      beta[mt][r] = exp2f(rm[mt][r] - mg);
      if (wid == 0 && lr == 0) lginv[row] = 1.f / lsum;
    }

  // sequential accumulate (deterministic, no atomics)
  #pragma unroll
  for (int w = 0; w < 4; ++w) {
    if (wid == w) {
      #pragma unroll
      for (int mt = 0; mt < 2; ++mt)
        #pragma unroll
        for (int nt = 0; nt < 4; ++nt)
          #pragma unroll
          for (int r = 0; r < 4; ++r) {
            const int row = mt * 16 + lg * 4 + r;
            const int col = nt * 16 + lr;
            obuf[row * 68 + col] += acc[mt][nt][r] * beta[mt][r];
          }
    }
    __syncthreads();
  }

  // readout: wave w -> rows [8w, 8w+8), each lane 8 consecutive cols
  {
    const int row = (wid << 3) + (lane >> 3);
    const int c0 = (lane & 7) * 8;
    const float li = lginv[row];
    const float4 v0 = *(const float4*)&obuf[row * 68 + c0];
    const float4 v1 = *(const float4*)&obuf[row * 68 + c0 + 4];
    s16x8 o;
    o[0] = (short)f2b(v0.x * li); o[1] = (short)f2b(v0.y * li);
    o[2] = (short)f2b(v0.z * li); o[3] = (short)f2b(v0.w * li);
    o[4] = (short)f2b(v1.x * li); o[5] = (short)f2b(v1.y * li);
    o[6] = (short)f2b(v1.z * li); o[7] = (short)f2b(v1.w * li);
    const int grow = base + row;
    *(s16x8*)(O + (size_t)(b * 2048 + grow) * 1024 + h * 64 + c0) = o;
  }
}

// ---------------- launch ----------------

extern "C" void kernel_launch(void* const* d_in, const int* in_sizes, int n_in,
                              void* d_out, int out_size, void* d_ws, size_t ws_size,
                              hipStream_t stream) {
  const float* x     = (const float*)d_in[0];
  const float* Wqkv  = (const float*)d_in[1];
  const float* bqkv  = (const float*)d_in[2];
  const float* Wproj = (const float*)d_in[3];
  const float* bproj = (const float*)d_in[4];
  float* out = (float*)d_out;

  char* ws = (char*)d_ws;
  unsigned short* xb    = (unsigned short*)(ws);
  unsigned short* wqkvt = (unsigned short*)(ws + (8ull << 20));
  unsigned short* wprjt = (unsigned short*)(ws + (14ull << 20));
  unsigned short* qb    = (unsigned short*)(ws + (16ull << 20));
  unsigned short* kb    = (unsigned short*)(ws + (24ull << 20));
  unsigned short* vT    = (unsigned short*)(ws + (32ull << 20));
  unsigned short* Ob    = (unsigned short*)(ws + (40ull << 20));

  // x: 4096*1024 = 4,194,304 elems = 1,048,576 float4
  convert_f32_bf16<<<4096, 256, 0, stream>>>(x, xb, 1048576);
  transpose_f32_bf16<<<dim3(96, 32), dim3(32, 8), 0, stream>>>(Wqkv, wqkvt, 1024, 3072);
  transpose_f32_bf16<<<dim3(32, 32), dim3(32, 8), 0, stream>>>(Wproj, wprjt, 1024, 1024);
  gemm128<0><<<dim3(24, 32), 256, 0, stream>>>(xb, wqkvt, bqkv, qb, kb, vT, nullptr);
  attn_fwd<<<2048, 256, 0, stream>>>(qb, kb, vT, Ob);
  gemm128<1><<<dim3(8, 32), 256, 0, stream>>>(Ob, wprjt, bproj, nullptr, nullptr, nullptr, out);
}

// Round 12
// 252.561 us; speedup vs baseline: 1.4448x; 1.0186x over previous
//
#include <hip/hip_runtime.h>
#include <hip/hip_bf16.h>

// Problem: B=2, L=2048, D=1024, H=16, HD=64. causal self-attention block.
// out = proj(attn(qkv(x)))
//
// Workspace layout (needs 48 MB):
//   [0,8M)   x_bf16      (4096,1024)
//   [8,14M)  WqkvT bf16  (3072,1024)   W^T so GEMM B-operand is [n][k]
//   [14,16M) WprojT bf16 (1024,1024)
//   [16,24M) q bf16 (B,H,L,HD)  pre-scaled by LOG2E/8 (softmax in base-2)
//   [24,32M) k bf16 (B,H,L,HD)
//   [32,40M) vT bf16 (B,H,HD,L)
//   [40,48M) Ob bf16 (B,L,H*HD); ALSO aliased as v_tmp (B,H,L,HD) between
//            gemm<0> and transpose_v (v_tmp dead before attn writes Ob).

typedef __attribute__((ext_vector_type(8))) short s16x8;
typedef __attribute__((ext_vector_type(4))) float f32x4;

__device__ __forceinline__ unsigned short f2b(float f) {
  __hip_bfloat16 h = __float2bfloat16(f);
  return *reinterpret_cast<unsigned short*>(&h);
}

// async global->LDS, 16B per lane. LDS dest is wave-uniform base (HW writes
// base + lane*16); global src is per-lane. Pointer cast = addrspacecast.
__device__ __forceinline__ void gl_lds16(const void* g, void* l) {
  __builtin_amdgcn_global_load_lds(
      (const __attribute__((address_space(1))) unsigned int*)g,
      (__attribute__((address_space(3))) unsigned int*)l,
      16, 0, 0);
}

// ---------------- converts ----------------

__global__ __launch_bounds__(256) void convert_f32_bf16(
    const float* __restrict__ in, unsigned short* __restrict__ out, int n4) {
  int i = blockIdx.x * 256 + threadIdx.x;
  if (i >= n4) return;
  float4 v = reinterpret_cast<const float4*>(in)[i];
  ushort4 o;
  o.x = f2b(v.x); o.y = f2b(v.y); o.z = f2b(v.z); o.w = f2b(v.w);
  reinterpret_cast<ushort4*>(out)[i] = o;
}

// out[c][r] = (bf16) in[r][c];  in is (R,C) fp32, out is (C,R) bf16
__global__ __launch_bounds__(256) void transpose_f32_bf16(
    const float* __restrict__ in, unsigned short* __restrict__ out, int R, int C) {
  __shared__ float tile[32][33];
  int cb = blockIdx.x * 32, rb = blockIdx.y * 32;
  int tx = threadIdx.x, ty = threadIdx.y;
  #pragma unroll
  for (int i = ty; i < 32; i += 8)
    tile[i][tx] = in[(size_t)(rb + i) * C + cb + tx];
  __syncthreads();
  #pragma unroll
  for (int i = ty; i < 32; i += 8)
    out[(size_t)(cb + i) * R + rb + tx] = f2b(tile[tx][i]);
}

// v_tmp (B,H,L,HD) -> vT (B,H,HD,L). 64x64 tiles, coalesced both sides.
// uint-padded LDS tile: write 2 lanes/bank, read 2 lanes/bank (both free).
__global__ __launch_bounds__(256) void transpose_v(
    const unsigned short* __restrict__ in, unsigned short* __restrict__ out) {
  __shared__ unsigned int tile[64][65];
  const int bh = blockIdx.y;       // 0..31
  const int l0 = blockIdx.x * 64;  // L tile
  const int tx = threadIdx.x;      // 0..63
  const int ty = threadIdx.y;      // 0..3
  #pragma unroll
  for (int i = ty; i < 64; i += 4)
    tile[i][tx] = in[((size_t)bh * 2048 + l0 + i) * 64 + tx];
  __syncthreads();
  #pragma unroll
  for (int i = ty; i < 64; i += 4)
    out[((size_t)bh * 64 + i) * 2048 + l0 + tx] = (unsigned short)tile[tx][i];
}

// ---------------- GEMM 128x128 tile, K=1024, BK=64 ----------------
// A (M,1024) bf16 row-major; Bt (N,1024) bf16 row-major (= B^T).
// MODE 0: QKV epilogue (scatter q/k/v_tmp, q scaled). MODE 1: fp32 out + bias.
// Grid XCD-swizzled (bijective: both grids are multiples of 8).
template <int MODE>
__global__ __launch_bounds__(256) void gemm128(
    const unsigned short* __restrict__ A, const unsigned short* __restrict__ Bt,
    const float* __restrict__ bias, unsigned short* __restrict__ qOut,
    unsigned short* __restrict__ kOut, unsigned short* __restrict__ vOut,
    float* __restrict__ fOut) {
  __shared__ char sA[16384];
  __shared__ char sB[16384];
  const int tid = threadIdx.x;
  const int wid = tid >> 6, lane = tid & 63;
  const int lg = lane >> 4, lr = lane & 15;
  const int wr = wid >> 1, wc = wid & 1;
  // XCD-aware bijective swizzle: each XCD gets a contiguous chunk of tiles.
  const int nwgx = gridDim.x;
  const int id = blockIdx.y * nwgx + blockIdx.x;
  const int cpx = (nwgx * gridDim.y) >> 3;
  const int sid = (id & 7) * cpx + (id >> 3);
  const int mb = sid / nwgx, nb = sid % nwgx;

  f32x4 acc[4][4];
  #pragma unroll
  for (int i = 0; i < 4; ++i)
    #pragma unroll
    for (int j = 0; j < 4; ++j) acc[i][j] = f32x4{0.f, 0.f, 0.f, 0.f};

  for (int ks = 0; ks < 16; ++ks) {
    __syncthreads();
    // stage A,Bt tiles (16KB each): LDS linear, global source pre-swizzled
    #pragma unroll
    for (int r = 0; r < 4; ++r) {
      const int chunk = r * 4 + wid;
      const int o = chunk * 1024 + lane * 16;
      const int row = o >> 7;              // tile row 0..127
      const int c16 = (o >> 4) & 7;        // 16B slot within 128B row
      const int swz = (c16 ^ (row & 7)) << 4;
      gl_lds16((const char*)A + ((size_t)(mb * 128 + row) * 1024 + ks * 64) * 2 + swz,
               sA + chunk * 1024);
      gl_lds16((const char*)Bt + ((size_t)(nb * 128 + row) * 1024 + ks * 64) * 2 + swz,
               sB + chunk * 1024);
    }
    __syncthreads();
    #pragma unroll
    for (int kb = 0; kb < 2; ++kb) {
      s16x8 af[4], bfr[4];
      #pragma unroll
      for (int mt = 0; mt < 4; ++mt) {
        const int rrow = wr * 64 + mt * 16 + lr;
        const int off = kb * 64 + lg * 16;
        af[mt] = *(const s16x8*)(sA + rrow * 128 + (off ^ ((rrow & 7) << 4)));
      }
      #pragma unroll
      for (int nt = 0; nt < 4; ++nt) {
        const int rrow = wc * 64 + nt * 16 + lr;
        const int off = kb * 64 + lg * 16;
        bfr[nt] = *(const s16x8*)(sB + rrow * 128 + (off ^ ((rrow & 7) << 4)));
      }
      #pragma unroll
      for (int mt = 0; mt < 4; ++mt)
        #pragma unroll
        for (int nt = 0; nt < 4; ++nt)
          acc[mt][nt] = __builtin_amdgcn_mfma_f32_16x16x32_bf16(
              af[mt], bfr[nt], acc[mt][nt], 0, 0, 0);
    }
  }

  // epilogue. C layout: col = lane&15, row = (lane>>4)*4 + r
  #pragma unroll
  for (int mt = 0; mt < 4; ++mt)
    #pragma unroll
    for (int nt = 0; nt < 4; ++nt)
      #pragma unroll
      for (int r = 0; r < 4; ++r) {
        const int m = mb * 128 + wr * 64 + mt * 16 + lg * 4 + r;
        const int n = nb * 128 + wc * 64 + nt * 16 + lr;
        float val = acc[mt][nt][r] + bias[n];
        if constexpr (MODE == 0) {
          const int b = m >> 11, ml = m & 2047;
          if (n < 1024) {           // q, scaled by HD^-0.5 * LOG2E (base-2 softmax)
            const int h = n >> 6, d = n & 63;
            qOut[((size_t)((b * 16 + h) * 2048 + ml)) * 64 + d] =
                f2b(val * 0.18033688f);
          } else if (n < 2048) {    // k
            const int nn = n - 1024, h = nn >> 6, d = nn & 63;
            kOut[((size_t)((b * 16 + h) * 2048 + ml)) * 64 + d] = f2b(val);
          } else {                  // v -> v_tmp (B,H,L,HD), coalesced like k;
            const int nn = n - 2048, h = nn >> 6, d = nn & 63;  // transposed later
            vOut[((size_t)((b * 16 + h) * 2048 + ml)) * 64 + d] = f2b(val);
          }
        } else {
          fOut[(size_t)m * 1024 + n] = val;
        }
      }
}

// ---------------- flash attention, kv-split ----------------
// One 256-thr block (4 waves) per (bh, qseg): 32 q-rows, kv tiles split
// across waves (t = wid, wid+4, ...). Per-wave online softmax; exact LDS
// merge at the end. Balanced: max 8 tiles/wave. K/V direct from global
// (L2-resident, heads clustered per XCD slot). Base-2 softmax.
// launch_bounds(256,2): VGPR cap 256 — (256,4) forced VGPR=64 and spilled
// ~600 MB/dispatch to scratch (R6). Measured R10: VGPR=128, no spills, 97us.
__global__ __launch_bounds__(256, 2) void attn_fwd(
    const unsigned short* __restrict__ Q, const unsigned short* __restrict__ Kb,
    const unsigned short* __restrict__ Vt, unsigned short* __restrict__ O) {
  __shared__ char sP[16384];        // per-wave [32 q][64 kv] bf16, swizzled
  __shared__ float obuf[32 * 68];   // merge accumulator, padded stride 68
  __shared__ float mlbuf[4][32][2]; // per-wave (m, l) per row
  __shared__ float lginv[32];       // 1 / l_global per row

  const int bid = blockIdx.x;
  const int idx = bid >> 3;
  const int bh = (bid & 7) * 4 + (idx & 3);  // cluster 4 heads per XCD slot
  const int qseg = 63 - (idx >> 2);          // heavy blocks first
  const int b = bh >> 4, h = bh & 15;
  const int tid = threadIdx.x;
  const int wid = tid >> 6, lane = tid & 63;
  const int lg = lane >> 4, lr = lane & 15;
  const int base = qseg * 32;

  // zero merge buffer (visible to all after the first merge barrier)
  for (int i = tid; i < 32 * 68; i += 256) obuf[i] = 0.f;

  // Q fragments (same 32 rows for all 4 waves)
  s16x8 qf[2][2];
  #pragma unroll
  for (int mt = 0; mt < 2; ++mt)
    #pragma unroll
    for (int kb = 0; kb < 2; ++kb) {
      const int row = base + mt * 16 + lr;
      qf[mt][kb] = *(const s16x8*)(Q + (size_t)(bh * 2048 + row) * 64 + kb * 32 + lg * 8);
    }

  f32x4 acc[2][4];
  float rm[2][4], rl[2][4];
  #pragma unroll
  for (int i = 0; i < 2; ++i)
    #pragma unroll
    for (int jj = 0; jj < 4; ++jj) {
      acc[i][jj] = f32x4{0.f, 0.f, 0.f, 0.f};
      rm[i][jj] = -INFINITY;
      rl[i][jj] = 0.f;
    }

  char* wbase = sP + wid * 4096;
  const int nkv = (qseg >> 1) + 1;

  for (int t = wid; t < nkv; t += 4) {
    const int kv0 = t * 64;

    // S = Q K^T  (32 q x 64 kv)
    f32x4 sfr[2][4];
    #pragma unroll
    for (int i = 0; i < 2; ++i)
      #pragma unroll
      for (int jj = 0; jj < 4; ++jj) sfr[i][jj] = f32x4{0.f, 0.f, 0.f, 0.f};
    #pragma unroll
    for (int kb = 0; kb < 2; ++kb) {
      s16x8 kf[4];
      #pragma unroll
      for (int nt = 0; nt < 4; ++nt)
        kf[nt] = *(const s16x8*)(Kb +
            (size_t)(bh * 2048 + kv0 + nt * 16 + lr) * 64 + kb * 32 + lg * 8);
      #pragma unroll
      for (int mt = 0; mt < 2; ++mt)
        #pragma unroll
        for (int nt = 0; nt < 4; ++nt)
          sfr[mt][nt] = __builtin_amdgcn_mfma_f32_16x16x32_bf16(
              qf[mt][kb], kf[nt], sfr[mt][nt], 0, 0, 0);
    }

    // issue V loads now so they overlap the softmax VALU chain
    s16x8 vf[2][4];
    #pragma unroll
    for (int kb = 0; kb < 2; ++kb)
      #pragma unroll
      for (int nt = 0; nt < 4; ++nt)
        vf[kb][nt] = *(const s16x8*)(Vt +
            (size_t)(bh * 64 + nt * 16 + lr) * 2048 + kv0 + kb * 32 + lg * 8);

    // mask + online softmax (base-2: S already scaled by LOG2E)
    #pragma unroll
    for (int mt = 0; mt < 2; ++mt) {
      #pragma unroll
      for (int r = 0; r < 4; ++r) {
        const int grow = base + mt * 16 + lg * 4 + r;
        float tmax = -INFINITY;
        #pragma unroll
        for (int nt = 0; nt < 4; ++nt) {
          const int col = kv0 + nt * 16 + lr;
          float s = sfr[mt][nt][r];
          if (col > grow) s = -INFINITY;
          sfr[mt][nt][r] = s;
          tmax = fmaxf(tmax, s);
        }
        tmax = fmaxf(tmax, __shfl_xor(tmax, 1));
        tmax = fmaxf(tmax, __shfl_xor(tmax, 2));
        tmax = fmaxf(tmax, __shfl_xor(tmax, 4));
        tmax = fmaxf(tmax, __shfl_xor(tmax, 8));
        const float mold = rm[mt][r];
        const float mnew = fmaxf(mold, tmax);
        const float alpha = exp2f(mold - mnew);
        float psum = 0.f;
        #pragma unroll
        for (int nt = 0; nt < 4; ++nt) {
          const float p = exp2f(sfr[mt][nt][r] - mnew);
          sfr[mt][nt][r] = p;
          psum += p;
        }
        psum += __shfl_xor(psum, 1);
        psum += __shfl_xor(psum, 2);
        psum += __shfl_xor(psum, 4);
        psum += __shfl_xor(psum, 8);
        rl[mt][r] = rl[mt][r] * alpha + psum;
        rm[mt][r] = mnew;
        #pragma unroll
        for (int nt = 0; nt < 4; ++nt) acc[mt][nt][r] *= alpha;
        // write P row (C-layout -> LDS), swizzled
        const int prow = mt * 16 + lg * 4 + r;
        #pragma unroll
        for (int nt = 0; nt < 4; ++nt) {
          const int pcolb = nt * 32 + lr * 2;
          *(unsigned short*)(wbase + prow * 128 + (pcolb ^ ((prow & 7) << 4))) =
              f2b(sfr[mt][nt][r]);
        }
      }
    }

    // PV: O += P V. P read back as A-fragments; vT rows give B-fragments.
    s16x8 pf[2][2];
    #pragma unroll
    for (int mt = 0; mt < 2; ++mt)
      #pragma unroll
      for (int kb = 0; kb < 2; ++kb) {
        const int prow = mt * 16 + lr;
        const int off = kb * 64 + lg * 16;
        pf[mt][kb] = *(const s16x8*)(wbase + prow * 128 + (off ^ ((prow & 7) << 4)));
      }
    #pragma unroll
    for (int mt = 0; mt < 2; ++mt)
      #pragma unroll
      for (int nt = 0; nt < 4; ++nt)
        #pragma unroll
        for (int kb = 0; kb < 2; ++kb)
          acc[mt][nt] = __builtin_amdgcn_mfma_f32_16x16x32_bf16(
              pf[mt][kb], vf[kb][nt], acc[mt][nt], 0, 0, 0);
  }

  // ---- merge the 4 partial (m, l, acc) sets ----
  // publish per-row (m, l); uniform across the 16 lr lanes, so lr==0 writes
  if (lr == 0) {
    #pragma unroll
    for (int mt = 0; mt < 2; ++mt)
      #pragma unroll
      for (int r = 0; r < 4; ++r) {
        const int row = mt * 16 + lg * 4 + r;
        mlbuf[wid][row][0] = rm[mt][r];
        mlbuf[wid][row][1] = rl[mt][r];
      }
  }
  __syncthreads();

  float beta[2][4];
  #pragma unroll
  for (int mt = 0; mt < 2; ++mt)
    #pragma unroll
    for (int r = 0; r < 4; ++r) {
      const int row = mt * 16 + lg * 4 + r;
      const float m0 = mlbuf[0][row][0], m1 = mlbuf[1][row][0];
      const float m2 = mlbuf[2][row][0], m3 = mlbuf[3][row][0];
      const float mg = fmaxf(fmaxf(m0, m1), fmaxf(m2, m3));
      const float lsum = mlbuf[0][row][1] * exp2f(m0 - mg)
                       + mlbuf[1][row][1] * exp2f(m1 - mg)
                       + mlbuf[2][row][1] * exp2f(m2 - mg)
                       + mlbuf[3][row][1] * exp2f(m3 - mg);
      beta[mt][r] = exp2f(rm[mt][r] - mg);
      if (wid == 0 && lr == 0) lginv[row] = 1.f / lsum;
    }

  // sequential accumulate (deterministic, no atomics)
  #pragma unroll
  for (int w = 0; w < 4; ++w) {
    if (wid == w) {
      #pragma unroll
      for (int mt = 0; mt < 2; ++mt)
        #pragma unroll
        for (int nt = 0; nt < 4; ++nt)
          #pragma unroll
          for (int r = 0; r < 4; ++r) {
            const int row = mt * 16 + lg * 4 + r;
            const int col = nt * 16 + lr;
            obuf[row * 68 + col] += acc[mt][nt][r] * beta[mt][r];
          }
    }
    __syncthreads();
  }

  // readout: wave w -> rows [8w, 8w+8), each lane 8 consecutive cols
  {
    const int row = (wid << 3) + (lane >> 3);
    const int c0 = (lane & 7) * 8;
    const float li = lginv[row];
    const float4 v0 = *(const float4*)&obuf[row * 68 + c0];
    const float4 v1 = *(const float4*)&obuf[row * 68 + c0 + 4];
    s16x8 o;
    o[0] = (short)f2b(v0.x * li); o[1] = (short)f2b(v0.y * li);
    o[2] = (short)f2b(v0.z * li); o[3] = (short)f2b(v0.w * li);
    o[4] = (short)f2b(v1.x * li); o[5] = (short)f2b(v1.y * li);
    o[6] = (short)f2b(v1.z * li); o[7] = (short)f2b(v1.w * li);
    const int grow = base + row;
    *(s16x8*)(O + (size_t)(b * 2048 + grow) * 1024 + h * 64 + c0) = o;
  }
}

// ---------------- launch ----------------

extern "C" void kernel_launch(void* const* d_in, const int* in_sizes, int n_in,
                              void* d_out, int out_size, void* d_ws, size_t ws_size,
                              hipStream_t stream) {
  const float* x     = (const float*)d_in[0];
  const float* Wqkv  = (const float*)d_in[1];
  const float* bqkv  = (const float*)d_in[2];
  const float* Wproj = (const float*)d_in[3];
  const float* bproj = (const float*)d_in[4];
  float* out = (float*)d_out;

  char* ws = (char*)d_ws;
  unsigned short* xb    = (unsigned short*)(ws);
  unsigned short* wqkvt = (unsigned short*)(ws + (8ull << 20));
  unsigned short* wprjt = (unsigned short*)(ws + (14ull << 20));
  unsigned short* qb    = (unsigned short*)(ws + (16ull << 20));
  unsigned short* kb    = (unsigned short*)(ws + (24ull << 20));
  unsigned short* vT    = (unsigned short*)(ws + (32ull << 20));
  unsigned short* Ob    = (unsigned short*)(ws + (40ull << 20));
  unsigned short* vtmp  = Ob;  // alias: dead before attn writes Ob

  // x: 4096*1024 = 4,194,304 elems = 1,048,576 float4
  convert_f32_bf16<<<4096, 256, 0, stream>>>(x, xb, 1048576);
  transpose_f32_bf16<<<dim3(96, 32), dim3(32, 8), 0, stream>>>(Wqkv, wqkvt, 1024, 3072);
  transpose_f32_bf16<<<dim3(32, 32), dim3(32, 8), 0, stream>>>(Wproj, wprjt, 1024, 1024);
  gemm128<0><<<dim3(24, 32), 256, 0, stream>>>(xb, wqkvt, bqkv, qb, kb, vtmp, nullptr);
  transpose_v<<<dim3(32, 32), dim3(64, 4), 0, stream>>>(vtmp, vT);
  attn_fwd<<<2048, 256, 0, stream>>>(qb, kb, vT, Ob);
  gemm128<1><<<dim3(8, 32), 256, 0, stream>>>(Ob, wprjt, bproj, nullptr, nullptr, nullptr, out);
}

// Round 13
// 232.715 us; speedup vs baseline: 1.5680x; 1.0853x over previous
//
#include <hip/hip_runtime.h>
#include <hip/hip_bf16.h>

// Problem: B=2, L=2048, D=1024, H=16, HD=64. causal self-attention block.
// out = proj(attn(qkv(x)))
//
// Workspace layout (needs 48 MB):
//   [0,8M)   x_bf16      (4096,1024)
//   [8,14M)  WqkvT bf16  (3072,1024)   W^T so GEMM B-operand is [n][k]
//   [14,16M) WprojT bf16 (1024,1024)
//   [16,24M) q bf16 (B,H,L,HD)  pre-scaled by LOG2E/8 (softmax in base-2)
//   [24,32M) k bf16 (B,H,L,HD)
//   [32,40M) vT bf16 (B,H,HD,L)
//   [40,48M) Ob bf16 (B,L,H*HD); ALSO aliased as v_tmp (B,H,L,HD) between
//            gemm<0> and transpose_v (v_tmp dead before attn writes Ob).

typedef __attribute__((ext_vector_type(8))) short s16x8;
typedef __attribute__((ext_vector_type(4))) float f32x4;
typedef __attribute__((ext_vector_type(16))) float f32x16;
typedef __attribute__((ext_vector_type(4))) unsigned int u32x4;

__device__ __forceinline__ unsigned short f2b(float f) {
  __hip_bfloat16 h = __float2bfloat16(f);
  return *reinterpret_cast<unsigned short*>(&h);
}

// pack 2 f32 -> 1 u32 of 2 bf16 (lo=a, hi=b). No builtin on gfx950 (m240).
__device__ __forceinline__ unsigned int cvtpk(float a, float b) {
  unsigned int r;
  asm("v_cvt_pk_bf16_f32 %0, %1, %2" : "=v"(r) : "v"(a), "v"(b));
  return r;
}
// v_permlane32_swap_b32: a[32..63] <-> b[0..31]
__device__ __forceinline__ void pl32swap(unsigned int& a, unsigned int& b) {
  asm("v_permlane32_swap_b32 %0, %1" : "+v"(a), "+v"(b));
}

// async global->LDS, 16B per lane. LDS dest is wave-uniform base (HW writes
// base + lane*16); global src is per-lane. Pointer cast = addrspacecast.
__device__ __forceinline__ void gl_lds16(const void* g, void* l) {
  __builtin_amdgcn_global_load_lds(
      (const __attribute__((address_space(1))) unsigned int*)g,
      (__attribute__((address_space(3))) unsigned int*)l,
      16, 0, 0);
}

// ---------------- converts ----------------

__global__ __launch_bounds__(256) void convert_f32_bf16(
    const float* __restrict__ in, unsigned short* __restrict__ out, int n4) {
  int i = blockIdx.x * 256 + threadIdx.x;
  if (i >= n4) return;
  float4 v = reinterpret_cast<const float4*>(in)[i];
  ushort4 o;
  o.x = f2b(v.x); o.y = f2b(v.y); o.z = f2b(v.z); o.w = f2b(v.w);
  reinterpret_cast<ushort4*>(out)[i] = o;
}

// out[c][r] = (bf16) in[r][c];  in is (R,C) fp32, out is (C,R) bf16
__global__ __launch_bounds__(256) void transpose_f32_bf16(
    const float* __restrict__ in, unsigned short* __restrict__ out, int R, int C) {
  __shared__ float tile[32][33];
  int cb = blockIdx.x * 32, rb = blockIdx.y * 32;
  int tx = threadIdx.x, ty = threadIdx.y;
  #pragma unroll
  for (int i = ty; i < 32; i += 8)
    tile[i][tx] = in[(size_t)(rb + i) * C + cb + tx];
  __syncthreads();
  #pragma unroll
  for (int i = ty; i < 32; i += 8)
    out[(size_t)(cb + i) * R + rb + tx] = f2b(tile[tx][i]);
}

// v_tmp (B,H,L,HD) -> vT (B,H,HD,L). 64x64 tiles, coalesced both sides.
__global__ __launch_bounds__(256) void transpose_v(
    const unsigned short* __restrict__ in, unsigned short* __restrict__ out) {
  __shared__ unsigned int tile[64][65];
  const int bh = blockIdx.y;       // 0..31
  const int l0 = blockIdx.x * 64;  // L tile
  const int tx = threadIdx.x;      // 0..63
  const int ty = threadIdx.y;      // 0..3
  #pragma unroll
  for (int i = ty; i < 64; i += 4)
    tile[i][tx] = in[((size_t)bh * 2048 + l0 + i) * 64 + tx];
  __syncthreads();
  #pragma unroll
  for (int i = ty; i < 64; i += 4)
    out[((size_t)bh * 64 + i) * 2048 + l0 + tx] = (unsigned short)tile[tx][i];
}

// ---------------- GEMM 128x128 tile, K=1024, BK=64 ----------------
// A (M,1024) bf16 row-major; Bt (N,1024) bf16 row-major (= B^T).
// MODE 0: QKV epilogue (scatter q/k/v_tmp, q scaled). MODE 1: fp32 out + bias.
// Grid XCD-swizzled (bijective: both grids are multiples of 8).
template <int MODE>
__global__ __launch_bounds__(256) void gemm128(
    const unsigned short* __restrict__ A, const unsigned short* __restrict__ Bt,
    const float* __restrict__ bias, unsigned short* __restrict__ qOut,
    unsigned short* __restrict__ kOut, unsigned short* __restrict__ vOut,
    float* __restrict__ fOut) {
  __shared__ char sA[16384];
  __shared__ char sB[16384];
  const int tid = threadIdx.x;
  const int wid = tid >> 6, lane = tid & 63;
  const int lg = lane >> 4, lr = lane & 15;
  const int wr = wid >> 1, wc = wid & 1;
  // XCD-aware bijective swizzle: each XCD gets a contiguous chunk of tiles.
  const int nwgx = gridDim.x;
  const int id = blockIdx.y * nwgx + blockIdx.x;
  const int cpx = (nwgx * gridDim.y) >> 3;
  const int sid = (id & 7) * cpx + (id >> 3);
  const int mb = sid / nwgx, nb = sid % nwgx;

  f32x4 acc[4][4];
  #pragma unroll
  for (int i = 0; i < 4; ++i)
    #pragma unroll
    for (int j = 0; j < 4; ++j) acc[i][j] = f32x4{0.f, 0.f, 0.f, 0.f};

  for (int ks = 0; ks < 16; ++ks) {
    __syncthreads();
    // stage A,Bt tiles (16KB each): LDS linear, global source pre-swizzled
    #pragma unroll
    for (int r = 0; r < 4; ++r) {
      const int chunk = r * 4 + wid;
      const int o = chunk * 1024 + lane * 16;
      const int row = o >> 7;              // tile row 0..127
      const int c16 = (o >> 4) & 7;        // 16B slot within 128B row
      const int swz = (c16 ^ (row & 7)) << 4;
      gl_lds16((const char*)A + ((size_t)(mb * 128 + row) * 1024 + ks * 64) * 2 + swz,
               sA + chunk * 1024);
      gl_lds16((const char*)Bt + ((size_t)(nb * 128 + row) * 1024 + ks * 64) * 2 + swz,
               sB + chunk * 1024);
    }
    __syncthreads();
    #pragma unroll
    for (int kb = 0; kb < 2; ++kb) {
      s16x8 af[4], bfr[4];
      #pragma unroll
      for (int mt = 0; mt < 4; ++mt) {
        const int rrow = wr * 64 + mt * 16 + lr;
        const int off = kb * 64 + lg * 16;
        af[mt] = *(const s16x8*)(sA + rrow * 128 + (off ^ ((rrow & 7) << 4)));
      }
      #pragma unroll
      for (int nt = 0; nt < 4; ++nt) {
        const int rrow = wc * 64 + nt * 16 + lr;
        const int off = kb * 64 + lg * 16;
        bfr[nt] = *(const s16x8*)(sB + rrow * 128 + (off ^ ((rrow & 7) << 4)));
      }
      #pragma unroll
      for (int mt = 0; mt < 4; ++mt)
        #pragma unroll
        for (int nt = 0; nt < 4; ++nt)
          acc[mt][nt] = __builtin_amdgcn_mfma_f32_16x16x32_bf16(
              af[mt], bfr[nt], acc[mt][nt], 0, 0, 0);
    }
  }

  // epilogue. C layout: col = lane&15, row = (lane>>4)*4 + r
  #pragma unroll
  for (int mt = 0; mt < 4; ++mt)
    #pragma unroll
    for (int nt = 0; nt < 4; ++nt)
      #pragma unroll
      for (int r = 0; r < 4; ++r) {
        const int m = mb * 128 + wr * 64 + mt * 16 + lg * 4 + r;
        const int n = nb * 128 + wc * 64 + nt * 16 + lr;
        float val = acc[mt][nt][r] + bias[n];
        if constexpr (MODE == 0) {
          const int b = m >> 11, ml = m & 2047;
          if (n < 1024) {           // q, scaled by HD^-0.5 * LOG2E (base-2 softmax)
            const int h = n >> 6, d = n & 63;
            qOut[((size_t)((b * 16 + h) * 2048 + ml)) * 64 + d] =
                f2b(val * 0.18033688f);
          } else if (n < 2048) {    // k
            const int nn = n - 1024, h = nn >> 6, d = nn & 63;
            kOut[((size_t)((b * 16 + h) * 2048 + ml)) * 64 + d] = f2b(val);
          } else {                  // v -> v_tmp (B,H,L,HD), coalesced like k;
            const int nn = n - 2048, h = nn >> 6, d = nn & 63;  // transposed later
            vOut[((size_t)((b * 16 + h) * 2048 + ml)) * 64 + d] = f2b(val);
          }
        } else {
          fOut[(size_t)m * 1024 + n] = val;
        }
      }
}

// ---------------- flash attention, swapped-QK^T 32x32 + kv-split ----------
// One 256-thr block (4 waves) per (bh, qseg). Each lane owns ONE q column
// (q = base + (lane&31)); S^T = K.Q^T via mfma_32x32x16 so the 32 P values
// of the q-row live in-register -> softmax = 31 in-reg max/add + 1
// shfl_xor(32). P -> PV B-operand via cvt_pk_bf16 + permlane32_swap (no LDS
// round-trip). PV swapped too: O^T = V^T.P^T, consuming vT directly.
// kv tiles split across waves (t = wid, wid+4, ...), exact merge via obuf.
// C-layout 32x32 (verified m74/m101): col=lane&31, row=(r&3)+8*(r>>2)+4*(lane>>5).
__global__ __launch_bounds__(256, 2) void attn_fwd(
    const unsigned short* __restrict__ Q, const unsigned short* __restrict__ Kb,
    const unsigned short* __restrict__ Vt, unsigned short* __restrict__ O) {
  __shared__ float obuf[32 * 68];   // merge accumulator [q][d], padded
  __shared__ float mlbuf[4][32][2]; // per-wave (m, l) per q
  __shared__ float lginv[32];       // 1 / l_global per q

  const int bid = blockIdx.x;
  const int idx = bid >> 3;
  const int bh = (bid & 7) * 4 + (idx & 3);  // cluster 4 heads per XCD slot
  const int qseg = 63 - (idx >> 2);          // heavy blocks first
  const int b = bh >> 4, h = bh & 15;
  const int tid = threadIdx.x;
  const int wid = tid >> 6, lane = tid & 63;
  const int ql = lane & 31, hi = lane >> 5;
  const int base = qseg * 32;
  const int q = base + ql;                   // this lane's q row

  for (int i = tid; i < 32 * 68; i += 256) obuf[i] = 0.f;

  // Q B-fragments hoisted: col=q, k(d) = ks*16 + hi*8 + i
  s16x8 qf[4];
  #pragma unroll
  for (int ks = 0; ks < 4; ++ks)
    qf[ks] = *(const s16x8*)(Q + (size_t)(bh * 2048 + q) * 64 + ks * 16 + hi * 8);

  f32x16 acc[2];                    // O^T: col=q, row=d_local (+32*db)
  #pragma unroll
  for (int db = 0; db < 2; ++db)
    #pragma unroll
    for (int r = 0; r < 16; ++r) acc[db][r] = 0.f;
  float rm = -INFINITY, rl = 0.f;

  const int nkv = (qseg >> 1) + 1;

  for (int t = wid; t < nkv; t += 4) {
    const int kv0 = t * 64;

    // S^T = K Q^T: A=K rows (kv), B=Q cols (q). pt[kvb]: kv block of 32.
    f32x16 pt[2];
    #pragma unroll
    for (int kvb = 0; kvb < 2; ++kvb)
      #pragma unroll
      for (int r = 0; r < 16; ++r) pt[kvb][r] = 0.f;
    #pragma unroll
    for (int kvb = 0; kvb < 2; ++kvb)
      #pragma unroll
      for (int ks = 0; ks < 4; ++ks) {
        s16x8 kf = *(const s16x8*)(Kb +
            (size_t)(bh * 2048 + kv0 + kvb * 32 + ql) * 64 + ks * 16 + hi * 8);
        pt[kvb] = __builtin_amdgcn_mfma_f32_32x32x16_bf16(
            kf, qf[ks], pt[kvb], 0, 0, 0);
      }

    // causal mask: only the diagonal tile needs it (wave-uniform branch)
    if (kv0 + 63 > base) {
      #pragma unroll
      for (int kvb = 0; kvb < 2; ++kvb)
        #pragma unroll
        for (int r = 0; r < 16; ++r) {
          const int kv = kv0 + kvb * 32 + (r & 3) + 8 * (r >> 2) + 4 * hi;
          pt[kvb][r] = (kv > q) ? -INFINITY : pt[kvb][r];
        }
    }

    // online softmax (base-2; q pre-scaled by LOG2E/8)
    float tm = -INFINITY;
    #pragma unroll
    for (int kvb = 0; kvb < 2; ++kvb)
      #pragma unroll
      for (int r = 0; r < 16; ++r) tm = fmaxf(tm, pt[kvb][r]);
    tm = fmaxf(tm, __shfl_xor(tm, 32));
    const float mnew = fmaxf(rm, tm);
    const float alpha = exp2f(rm - mnew);
    float psum = 0.f;
    #pragma unroll
    for (int kvb = 0; kvb < 2; ++kvb)
      #pragma unroll
      for (int r = 0; r < 16; ++r) {
        const float p = exp2f(pt[kvb][r] - mnew);
        pt[kvb][r] = p;
        psum += p;
      }
    psum += __shfl_xor(psum, 32);
    rl = rl * alpha + psum;
    rm = mnew;
    #pragma unroll
    for (int db = 0; db < 2; ++db)
      #pragma unroll
      for (int r = 0; r < 16; ++r) acc[db][r] *= alpha;

    // pack P^T -> B-frags: per kvb, ks2: kv = ks2*16 + hi*8 + i.
    // lane<32 regs r0..r0+3 = kv {0..3}, r0+4..7 = kv {8..11} (+4hi).
    // swap(pk(p0,p1), pk(p4,p5)) -> w0 (kv0,1 | kv8,9), w2 (kv4,5 | kv12,13).
    s16x8 pfrag[2][2];
    #pragma unroll
    for (int kvb = 0; kvb < 2; ++kvb)
      #pragma unroll
      for (int ks2 = 0; ks2 < 2; ++ks2) {
        const int r0 = ks2 * 8;
        unsigned int x = cvtpk(pt[kvb][r0 + 0], pt[kvb][r0 + 1]);
        unsigned int y = cvtpk(pt[kvb][r0 + 2], pt[kvb][r0 + 3]);
        unsigned int z = cvtpk(pt[kvb][r0 + 4], pt[kvb][r0 + 5]);
        unsigned int w = cvtpk(pt[kvb][r0 + 6], pt[kvb][r0 + 7]);
        pl32swap(x, z);
        pl32swap(y, w);
        u32x4 pw;
        pw[0] = x; pw[1] = y; pw[2] = z; pw[3] = w;
        pfrag[kvb][ks2] = __builtin_bit_cast(s16x8, pw);
      }

    // PV swapped: O^T += V^T P^T. A=V^T rows (d), B=P^T cols (q).
    #pragma unroll
    for (int db = 0; db < 2; ++db)
      #pragma unroll
      for (int kvb = 0; kvb < 2; ++kvb)
        #pragma unroll
        for (int ks2 = 0; ks2 < 2; ++ks2) {
          s16x8 vf = *(const s16x8*)(Vt +
              (size_t)(bh * 64 + db * 32 + ql) * 2048 +
              kv0 + kvb * 32 + ks2 * 16 + hi * 8);
          acc[db] = __builtin_amdgcn_mfma_f32_32x32x16_bf16(
              vf, pfrag[kvb][ks2], acc[db], 0, 0, 0);
        }
  }

  // ---- merge the 4 partial (m, l, acc) sets ----
  if (lane < 32) {
    mlbuf[wid][ql][0] = rm;
    mlbuf[wid][ql][1] = rl;
  }
  __syncthreads();

  const float m0 = mlbuf[0][ql][0], m1 = mlbuf[1][ql][0];
  const float m2 = mlbuf[2][ql][0], m3 = mlbuf[3][ql][0];
  const float mg = fmaxf(fmaxf(m0, m1), fmaxf(m2, m3));
  const float lsum = mlbuf[0][ql][1] * exp2f(m0 - mg)
                   + mlbuf[1][ql][1] * exp2f(m1 - mg)
                   + mlbuf[2][ql][1] * exp2f(m2 - mg)
                   + mlbuf[3][ql][1] * exp2f(m3 - mg);
  const float beta = exp2f(rm - mg);
  if (wid == 0 && lane < 32) lginv[ql] = 1.f / lsum;

  // sequential accumulate (deterministic, no atomics)
  #pragma unroll
  for (int w = 0; w < 4; ++w) {
    if (wid == w) {
      #pragma unroll
      for (int db = 0; db < 2; ++db)
        #pragma unroll
        for (int r = 0; r < 16; ++r) {
          const int d = db * 32 + (r & 3) + 8 * (r >> 2) + 4 * hi;
          obuf[ql * 68 + d] += acc[db][r] * beta;
        }
    }
    __syncthreads();
  }

  // readout: wave w -> rows [8w, 8w+8), each lane 8 consecutive cols
  {
    const int row = (wid << 3) + (lane >> 3);
    const int c0 = (lane & 7) * 8;
    const float li = lginv[row];
    const float4 v0 = *(const float4*)&obuf[row * 68 + c0];
    const float4 v1 = *(const float4*)&obuf[row * 68 + c0 + 4];
    s16x8 o;
    o[0] = (short)f2b(v0.x * li); o[1] = (short)f2b(v0.y * li);
    o[2] = (short)f2b(v0.z * li); o[3] = (short)f2b(v0.w * li);
    o[4] = (short)f2b(v1.x * li); o[5] = (short)f2b(v1.y * li);
    o[6] = (short)f2b(v1.z * li); o[7] = (short)f2b(v1.w * li);
    const int grow = base + row;
    *(s16x8*)(O + (size_t)(b * 2048 + grow) * 1024 + h * 64 + c0) = o;
  }
}

// ---------------- launch ----------------

extern "C" void kernel_launch(void* const* d_in, const int* in_sizes, int n_in,
                              void* d_out, int out_size, void* d_ws, size_t ws_size,
                              hipStream_t stream) {
  const float* x     = (const float*)d_in[0];
  const float* Wqkv  = (const float*)d_in[1];
  const float* bqkv  = (const float*)d_in[2];
  const float* Wproj = (const float*)d_in[3];
  const float* bproj = (const float*)d_in[4];
  float* out = (float*)d_out;

  char* ws = (char*)d_ws;
  unsigned short* xb    = (unsigned short*)(ws);
  unsigned short* wqkvt = (unsigned short*)(ws + (8ull << 20));
  unsigned short* wprjt = (unsigned short*)(ws + (14ull << 20));
  unsigned short* qb    = (unsigned short*)(ws + (16ull << 20));
  unsigned short* kb    = (unsigned short*)(ws + (24ull << 20));
  unsigned short* vT    = (unsigned short*)(ws + (32ull << 20));
  unsigned short* Ob    = (unsigned short*)(ws + (40ull << 20));
  unsigned short* vtmp  = Ob;  // alias: dead before attn writes Ob

  // x: 4096*1024 = 4,194,304 elems = 1,048,576 float4
  convert_f32_bf16<<<4096, 256, 0, stream>>>(x, xb, 1048576);
  transpose_f32_bf16<<<dim3(96, 32), dim3(32, 8), 0, stream>>>(Wqkv, wqkvt, 1024, 3072);
  transpose_f32_bf16<<<dim3(32, 32), dim3(32, 8), 0, stream>>>(Wproj, wprjt, 1024, 1024);
  gemm128<0><<<dim3(24, 32), 256, 0, stream>>>(xb, wqkvt, bqkv, qb, kb, vtmp, nullptr);
  transpose_v<<<dim3(32, 32), dim3(64, 4), 0, stream>>>(vtmp, vT);
  attn_fwd<<<2048, 256, 0, stream>>>(qb, kb, vT, Ob);
  gemm128<1><<<dim3(8, 32), 256, 0, stream>>>(Ob, wprjt, bproj, nullptr, nullptr, nullptr, out);
}